// Round 2
// baseline (112.327 us; speedup 1.0000x reference)
//
#include <hip/hip_runtime.h>
#include <math.h>

constexpr int BS = 32, NV = 321, PL = 12, DM = 128;
constexpr int KT = 32;  // int(64*0.5) patches masked by time criterion
constexpr int KF = 25;  // int(64*0.4) patches masked by freq criterion
constexpr int VB = 8;       // variables per block
constexpr int NCHUNK = 41;  // 40 full chunks + 1 tail chunk (nv=1)
constexpr int SST = 72;     // score row stride: (72*vv+p)%32 -> <=2-way (free)

// map float -> uint such that uint order == float order (total, -0 < +0)
__device__ __forceinline__ unsigned ord(float f) {
  unsigned u = __float_as_uint(f);
  return ((int)u < 0) ? ~u : (u | 0x80000000u);
}

// ---------------------------------------------------------------------------
// prep: ws floats [0,144) Mt[l][i] (l-major: Mt[l][i] = sum_d Win[i][d]Wout[d][l]),
//       [144,156) c = b_in@W_out, [156,168) St = tt*colsum(W_out),
//       [168,180) Sf = ft*colsum(W_out), [180,192) b_out.
// ---------------------------------------------------------------------------
__global__ void prep_kernel(const float* __restrict__ W_in,
                            const float* __restrict__ b_in,
                            const float* __restrict__ W_out,
                            const float* __restrict__ b_out,
                            const float* __restrict__ tt,
                            const float* __restrict__ ft,
                            float* __restrict__ ws) {
  const int t = threadIdx.x;
  if (t < 144) {
    const int l = t / 12, i = t % 12;
    const float4* Wi = (const float4*)(W_in + i * DM);
    float s = 0.f;
#pragma unroll 8
    for (int d4 = 0; d4 < 32; ++d4) {
      float4 a = Wi[d4];
      const float* wo = W_out + d4 * 48 + l;
      s += a.x * wo[0] + a.y * wo[12] + a.z * wo[24] + a.w * wo[36];
    }
    ws[t] = s;
  } else if (t < 168) {
    const int l = (t - 144) % 12;
    float cs = 0.f, cb = 0.f;
#pragma unroll 8
    for (int d = 0; d < DM; ++d) {
      float w = W_out[d * 12 + l];
      cs += w;
      cb += b_in[d] * w;
    }
    if (t < 156) {
      ws[144 + l] = cb;
      ws[156 + l] = tt[0] * cs;
    } else {
      ws[168 + l] = ft[0] * cs;
    }
  } else if (t < 180) {
    ws[180 + (t - 168)] = b_out[t - 168];
  }
}

// ---------------------------------------------------------------------------
// fused: one block per (b, 8-var chunk), 512 threads, ONE patch-var/thread
// (p = t>>3, vv = t&7: lanes sweep vv -> 384B contiguous runs). x stays in
// registers end-to-end; scores go through LDS for the per-(b,v) wave ranking;
// keep-masks pass through 128B of LDS (no global round-trip). Decode reads the
// 192 prep constants via wave-uniform SCALAR loads.
// ---------------------------------------------------------------------------
__global__ __launch_bounds__(512, 8) void fused_kernel(
    const float* __restrict__ x, const float* __restrict__ prep,
    float* __restrict__ out) {
  __shared__ float scv[VB * SST];
  __shared__ float sfs[VB * SST];
  __shared__ unsigned long long smT[VB], smF[VB];

  const int t = threadIdx.x;
  const int chunk = blockIdx.x;  // 0..40
  const int b = blockIdx.y;      // 0..31
  const int v0 = chunk * VB;
  const bool full = (chunk < 40);
  const int nv = full ? VB : 1;

  const float* xb = x + ((size_t)(b * 64) * NV + v0) * PL;

  int p, vv;
  bool valid;  // wave-uniform in the tail chunk (t<64 == wave 0)
  if (full) {
    p = t >> 3;
    vv = t & 7;
    valid = true;
  } else {
    p = t & 63;
    vv = 0;
    valid = (t < 64);
  }

  float xv[12];
  if (valid) {
    const float4* src = (const float4*)(xb + ((size_t)p * NV + vv) * PL);
    float4 a = src[0], bb = src[1], c = src[2];
    xv[0] = a.x;  xv[1] = a.y;  xv[2] = a.z;  xv[3] = a.w;
    xv[4] = bb.x; xv[5] = bb.y; xv[6] = bb.z; xv[7] = bb.w;
    xv[8] = c.x;  xv[9] = c.y;  xv[10] = c.z; xv[11] = c.w;

    // coefficient of variation: std(ddof=1)/(mean+1e-6)
    float s = 0.f;
#pragma unroll
    for (int i = 0; i < 12; ++i) s += xv[i];
    const float m = s * (1.0f / 12.0f);
    float ss = 0.f;
#pragma unroll
    for (int i = 0; i < 12; ++i) {
      float d = xv[i] - m;
      ss += d * d;
    }
    const float cv = sqrtf(ss * (1.0f / 11.0f)) / (m + 1e-6f);

    // mean |rfft12| over 7 bins, even/odd folded exact 30-degree DFT
    const float H = 0.86602540378443864676f;  // sqrt(3)/2
    const float e1 = xv[1] + xv[11], e2 = xv[2] + xv[10], e3 = xv[3] + xv[9],
                e4 = xv[4] + xv[8], e5 = xv[5] + xv[7];
    const float o1 = xv[1] - xv[11], o2 = xv[2] - xv[10], o3 = xv[3] - xv[9],
                o4 = xv[4] - xv[8], o5 = xv[5] - xv[7];
    float mag = fabsf(xv[0] + xv[6] + e1 + e2 + e3 + e4 + e5);  // k=0
    float re = xv[0] - xv[6] + H * (e1 - e5) + 0.5f * (e2 - e4);
    float im = 0.5f * (o1 + o5) + H * (o2 + o4) + o3;
    mag += sqrtf(re * re + im * im);  // k=1
    re = xv[0] + xv[6] + 0.5f * (e1 + e5) - 0.5f * (e2 + e4) - e3;
    im = H * (o1 + o2 - o4 - o5);
    mag += sqrtf(re * re + im * im);  // k=2
    re = xv[0] - xv[6] - e2 + e4;
    im = o1 - o3 + o5;
    mag += sqrtf(re * re + im * im);  // k=3
    re = xv[0] + xv[6] - 0.5f * (e1 + e2 + e4 + e5) + e3;
    im = H * (o1 - o2 + o4 - o5);
    mag += sqrtf(re * re + im * im);  // k=4
    re = xv[0] - xv[6] + H * (e5 - e1) + 0.5f * (e2 - e4);
    im = 0.5f * (o1 + o5) - H * (o2 + o4) + o3;
    mag += sqrtf(re * re + im * im);  // k=5
    re = xv[0] + xv[6] - e1 + e2 - e3 + e4 - e5;
    mag += fabsf(re);  // k=6
    const float fs = mag * (1.0f / 7.0f);

    scv[vv * SST + p] = cv;
    sfs[vv * SST + p] = fs;
  }
  __syncthreads();

  // ---- dual radix top-k: wave wv ranks variable wv, lane = p ----
  const int wv = t >> 6, lane = t & 63;
  if (wv < nv) {  // wave-uniform
    const unsigned ut = ord(scv[wv * SST + lane]);   // rank KT LARGEST cv
    const unsigned uf = ~ord(sfs[wv * SST + lane]);  // rank KF SMALLEST fs
    unsigned tht = 0, thf = 0;
#pragma unroll
    for (int bit = 31; bit >= 0; --bit) {
      const unsigned ct = tht | (1u << bit);
      const unsigned cf = thf | (1u << bit);
      const unsigned long long bt = __ballot(ut >= ct);
      const unsigned long long bf = __ballot(uf >= cf);
      if (__popcll(bt) >= KT) tht = ct;
      if (__popcll(bf) >= KF) thf = cf;
    }
    const unsigned long long pre = (1ull << lane) - 1ull;
    const int gt_t = __popcll(__ballot(ut > tht));
    const int rt = __popcll(__ballot(ut == tht) & pre);
    const bool masked_t = (ut > tht) || ((ut == tht) && (rt < KT - gt_t));
    const int gt_f = __popcll(__ballot(uf > thf));
    const int rf = __popcll(__ballot(uf == thf) & pre);
    const bool masked_f = (uf > thf) || ((uf == thf) && (rf < KF - gt_f));
    const unsigned long long bkt = __ballot(!masked_t);
    const unsigned long long bkf = __ballot(!masked_f);
    if (lane == 0) {
      smT[wv] = bkt;
      smF[wv] = bkf;
    }
  }
  __syncthreads();

  // ---- decode from registers; M via wave-uniform scalar loads ----
  if (valid) {
    const bool kt = (smT[vv] >> p) & 1ull;
    const bool kf = (smF[vv] >> p) & 1ull;
    float o[12];
#pragma unroll
    for (int l0 = 0; l0 < 12; l0 += 4) {
#pragma unroll
      for (int l = l0; l < l0 + 4; ++l) {
        const float* Ml = prep + l * 12;  // Mt row l: contiguous, uniform
        float e = prep[144 + l];
#pragma unroll
        for (int i = 0; i < 12; ++i) e = fmaf(xv[i], Ml[i], e);
        const float at = kt ? e : prep[156 + l];
        const float af = kf ? e : prep[168 + l];
        o[l] = 0.5f * (at + af) + prep[180 + l];
      }
      if (l0 < 8) __builtin_amdgcn_sched_barrier(0);  // cap SGPR liveness
    }
    float* op = out + ((size_t)(b * 64 + p) * NV + v0 + vv) * PL;
    ((float4*)op)[0] = make_float4(o[0], o[1], o[2], o[3]);
    ((float4*)op)[1] = make_float4(o[4], o[5], o[6], o[7]);
    ((float4*)op)[2] = make_float4(o[8], o[9], o[10], o[11]);
  }
}

extern "C" void kernel_launch(void* const* d_in, const int* in_sizes, int n_in,
                              void* d_out, int out_size, void* d_ws,
                              size_t ws_size, hipStream_t stream) {
  const float* x = (const float*)d_in[0];
  const float* W_in = (const float*)d_in[1];
  const float* b_in = (const float*)d_in[2];
  const float* W_out = (const float*)d_in[3];
  const float* b_out = (const float*)d_in[4];
  const float* tt = (const float*)d_in[5];
  const float* ft = (const float*)d_in[6];
  float* out = (float*)d_out;
  float* ws = (float*)d_ws;  // 192 floats of decode constants

  hipLaunchKernelGGL(prep_kernel, dim3(1), dim3(192), 0, stream, W_in, b_in,
                     W_out, b_out, tt, ft, ws);
  hipLaunchKernelGGL(fused_kernel, dim3(NCHUNK, BS), dim3(512), 0, stream, x,
                     ws, out);
}

// Round 3
// 110.637 us; speedup vs baseline: 1.0153x; 1.0153x over previous
//
#include <hip/hip_runtime.h>
#include <math.h>

constexpr int BS = 32, NV = 321, PL = 12, DM = 128;
constexpr int KT = 32;  // int(64*0.5) patches masked by time criterion
constexpr int KF = 25;  // int(64*0.4) patches masked by freq criterion
constexpr int VB = 8;       // variables per block
constexpr int NCHUNK = 41;  // 40 full chunks + 1 tail chunk (nv=1)
constexpr int SST = 72;     // score row stride: (72*vv+p)%32 -> <=2-way (free)
constexpr int WROW = 132;   // padded sWin row stride: 132%4==0, 132%32==4 -> <=2-way

// map float -> uint such that uint order == float order (total, -0 < +0)
__device__ __forceinline__ unsigned ord(float f) {
  unsigned u = __float_as_uint(f);
  return ((int)u < 0) ? ~u : (u | 0x80000000u);
}

// ---------------------------------------------------------------------------
// ONE kernel, ONE launch. Each block (b, 8-var chunk; 512 thr, 1 patch-var/thr)
// redundantly computes the tiny decode constants from staged weights (phase
// overlapped with the score phase), ranks per-(b,v) with wave ballots, and
// decodes. Removes the serialized 1-block prep launch + 2nd dispatch entirely.
// spp: [0,144) Mt[l][i] = sum_d Win[i][d]*Wout[d][l], [144) c=b_in@W_out,
//      [156) St=tt*colsum, [168) Sf=ft*colsum.
// ---------------------------------------------------------------------------
__global__ __launch_bounds__(512, 8) void fused_kernel(
    const float* __restrict__ x, const float* __restrict__ W_in,
    const float* __restrict__ b_in, const float* __restrict__ W_out,
    const float* __restrict__ b_out, const float* __restrict__ tt,
    const float* __restrict__ ft, float* __restrict__ out) {
  __shared__ __align__(16) float sWin[12 * WROW];   // padded [12][132]
  __shared__ __align__(16) float sWout[DM * PL];    // [128][12]
  __shared__ __align__(16) float sbin[DM];
  __shared__ __align__(16) float spp[180];
  __shared__ float scv[VB * SST];
  __shared__ float sfs[VB * SST];
  __shared__ unsigned long long smT[VB], smF[VB];

  const int t = threadIdx.x;
  const int chunk = blockIdx.x;  // 0..40
  const int b = blockIdx.y;      // 0..31
  const int v0 = chunk * VB;
  const bool full = (chunk < 40);
  const int nv = full ? VB : 1;

  const float* xb = x + ((size_t)(b * 64) * NV + v0) * PL;

  int p, vv;
  bool valid;  // wave-uniform in the tail chunk (t<64 == wave 0)
  if (full) {
    p = t >> 3;
    vv = t & 7;
    valid = true;
  } else {
    p = t & 63;
    vv = 0;
    valid = (t < 64);
  }

  // ---- issue x loads early (latency hides under weight staging) ----
  float4 a0, a1, a2;
  if (valid) {
    const float4* src = (const float4*)(xb + ((size_t)p * NV + vv) * PL);
    a0 = src[0];
    a1 = src[1];
    a2 = src[2];
  }

  // ---- stage weights into LDS (coalesced float4) ----
  if (t < 384) {
    float4 w = ((const float4*)W_in)[t];
    const int r = t >> 5, cq = (t & 31) << 2;  // row, col of [12][128]
    *(float4*)(sWin + r * WROW + cq) = w;
    ((float4*)sWout)[t] = ((const float4*)W_out)[t];
  }
  if (t < 32) ((float4*)sbin)[t] = ((const float4*)b_in)[t];
  __syncthreads();

  // ---- per-block prep (threads <180) runs CONCURRENTLY with scores ----
  if (t < 144) {
    const int l = t / 12, i = t % 12;
    const float* wi = sWin + i * WROW;
    float s = 0.f;
#pragma unroll 4
    for (int d = 0; d < DM; ++d) s = fmaf(wi[d], sWout[d * 12 + l], s);
    spp[l * 12 + i] = s;
  } else if (t < 180) {
    const int l = (t - 144) % 12;
    float cs = 0.f, cb = 0.f;
#pragma unroll 4
    for (int d = 0; d < DM; ++d) {
      const float w = sWout[d * 12 + l];
      cs += w;
      cb = fmaf(sbin[d], w, cb);
    }
    if (t < 156)
      spp[144 + l] = cb;
    else if (t < 168)
      spp[156 + l] = tt[0] * cs;
    else
      spp[168 + l] = ft[0] * cs;
  }

  // ---- per-patch scores from registers ----
  float xv[12];
  if (valid) {
    xv[0] = a0.x;  xv[1] = a0.y;  xv[2] = a0.z;  xv[3] = a0.w;
    xv[4] = a1.x;  xv[5] = a1.y;  xv[6] = a1.z;  xv[7] = a1.w;
    xv[8] = a2.x;  xv[9] = a2.y;  xv[10] = a2.z; xv[11] = a2.w;

    // coefficient of variation: std(ddof=1)/(mean+1e-6)
    float s = 0.f;
#pragma unroll
    for (int i = 0; i < 12; ++i) s += xv[i];
    const float m = s * (1.0f / 12.0f);
    float ss = 0.f;
#pragma unroll
    for (int i = 0; i < 12; ++i) {
      float d = xv[i] - m;
      ss += d * d;
    }
    const float cv = sqrtf(ss * (1.0f / 11.0f)) / (m + 1e-6f);

    // mean |rfft12| over 7 bins, even/odd folded exact 30-degree DFT
    const float H = 0.86602540378443864676f;  // sqrt(3)/2
    const float e1 = xv[1] + xv[11], e2 = xv[2] + xv[10], e3 = xv[3] + xv[9],
                e4 = xv[4] + xv[8], e5 = xv[5] + xv[7];
    const float o1 = xv[1] - xv[11], o2 = xv[2] - xv[10], o3 = xv[3] - xv[9],
                o4 = xv[4] - xv[8], o5 = xv[5] - xv[7];
    float mag = fabsf(xv[0] + xv[6] + e1 + e2 + e3 + e4 + e5);  // k=0
    float re = xv[0] - xv[6] + H * (e1 - e5) + 0.5f * (e2 - e4);
    float im = 0.5f * (o1 + o5) + H * (o2 + o4) + o3;
    mag += sqrtf(re * re + im * im);  // k=1
    re = xv[0] + xv[6] + 0.5f * (e1 + e5) - 0.5f * (e2 + e4) - e3;
    im = H * (o1 + o2 - o4 - o5);
    mag += sqrtf(re * re + im * im);  // k=2
    re = xv[0] - xv[6] - e2 + e4;
    im = o1 - o3 + o5;
    mag += sqrtf(re * re + im * im);  // k=3
    re = xv[0] + xv[6] - 0.5f * (e1 + e2 + e4 + e5) + e3;
    im = H * (o1 - o2 + o4 - o5);
    mag += sqrtf(re * re + im * im);  // k=4
    re = xv[0] - xv[6] + H * (e5 - e1) + 0.5f * (e2 - e4);
    im = 0.5f * (o1 + o5) - H * (o2 + o4) + o3;
    mag += sqrtf(re * re + im * im);  // k=5
    re = xv[0] + xv[6] - e1 + e2 - e3 + e4 - e5;
    mag += fabsf(re);  // k=6
    const float fs = mag * (1.0f / 7.0f);

    scv[vv * SST + p] = cv;
    sfs[vv * SST + p] = fs;
  }
  __syncthreads();

  // ---- dual radix top-k: wave wv ranks variable wv, lane = patch ----
  const int wv = t >> 6, lane = t & 63;
  if (wv < nv) {  // wave-uniform
    const unsigned ut = ord(scv[wv * SST + lane]);   // rank KT LARGEST cv
    const unsigned uf = ~ord(sfs[wv * SST + lane]);  // rank KF SMALLEST fs
    unsigned tht = 0, thf = 0;
#pragma unroll
    for (int bit = 31; bit >= 0; --bit) {
      const unsigned ct = tht | (1u << bit);
      const unsigned cf = thf | (1u << bit);
      const unsigned long long bt = __ballot(ut >= ct);
      const unsigned long long bf = __ballot(uf >= cf);
      if (__popcll(bt) >= KT) tht = ct;
      if (__popcll(bf) >= KF) thf = cf;
    }
    const unsigned long long pre = (1ull << lane) - 1ull;
    const int gt_t = __popcll(__ballot(ut > tht));
    const int rt = __popcll(__ballot(ut == tht) & pre);
    const bool masked_t = (ut > tht) || ((ut == tht) && (rt < KT - gt_t));
    const int gt_f = __popcll(__ballot(uf > thf));
    const int rf = __popcll(__ballot(uf == thf) & pre);
    const bool masked_f = (uf > thf) || ((uf == thf) && (rf < KF - gt_f));
    const unsigned long long bkt = __ballot(!masked_t);
    const unsigned long long bkf = __ballot(!masked_f);
    if (lane == 0) {
      smT[wv] = bkt;
      smF[wv] = bkf;
    }
  }

  // ---- E = c + xv . Mt  (LDS broadcast reads: uniform addr = free) ----
  float E[12];
  if (valid) {
#pragma unroll
    for (int l = 0; l < 12; ++l) {
      const float4* Ml4 = (const float4*)(spp + l * 12);
      const float4 m0 = Ml4[0], m1 = Ml4[1], m2 = Ml4[2];
      float e = spp[144 + l];
      e = fmaf(xv[0], m0.x, e);  e = fmaf(xv[1], m0.y, e);
      e = fmaf(xv[2], m0.z, e);  e = fmaf(xv[3], m0.w, e);
      e = fmaf(xv[4], m1.x, e);  e = fmaf(xv[5], m1.y, e);
      e = fmaf(xv[6], m1.z, e);  e = fmaf(xv[7], m1.w, e);
      e = fmaf(xv[8], m2.x, e);  e = fmaf(xv[9], m2.y, e);
      e = fmaf(xv[10], m2.z, e); e = fmaf(xv[11], m2.w, e);
      E[l] = e;
    }
  }
  __syncthreads();

  // ---- blend + store ----
  if (valid) {
    const bool kt = (smT[vv] >> p) & 1ull;
    const bool kf = (smF[vv] >> p) & 1ull;
    float o[12];
#pragma unroll
    for (int l = 0; l < 12; ++l) {
      const float e = E[l];
      const float at = kt ? e : spp[156 + l];
      const float af = kf ? e : spp[168 + l];
      o[l] = 0.5f * (at + af) + b_out[l];  // b_out[l]: uniform -> s_load
    }
    float* op = out + ((size_t)(b * 64 + p) * NV + v0 + vv) * PL;
    ((float4*)op)[0] = make_float4(o[0], o[1], o[2], o[3]);
    ((float4*)op)[1] = make_float4(o[4], o[5], o[6], o[7]);
    ((float4*)op)[2] = make_float4(o[8], o[9], o[10], o[11]);
  }
}

extern "C" void kernel_launch(void* const* d_in, const int* in_sizes, int n_in,
                              void* d_out, int out_size, void* d_ws,
                              size_t ws_size, hipStream_t stream) {
  const float* x = (const float*)d_in[0];
  const float* W_in = (const float*)d_in[1];
  const float* b_in = (const float*)d_in[2];
  const float* W_out = (const float*)d_in[3];
  const float* b_out = (const float*)d_in[4];
  const float* tt = (const float*)d_in[5];
  const float* ft = (const float*)d_in[6];
  float* out = (float*)d_out;

  hipLaunchKernelGGL(fused_kernel, dim3(NCHUNK, BS), dim3(512), 0, stream, x,
                     W_in, b_in, W_out, b_out, tt, ft, out);
}